// Round 1
// baseline (180.534 us; speedup 1.0000x reference)
//
#include <hip/hip_runtime.h>

// Soft VQ encoding, fused bf16-MFMA implementation.
//   X:(8,16384,128) fp32, C:(128,128) fp32, S:(128) fp32 -> E:(8,128,128) fp32
// Structure: 512 blocks x 256 threads (4 waves), __launch_bounds__(256,2).
//   Each block: b = bid>>6, handles 4 chunks of 64 rows (256 consecutive rows).
//   matmul1: DT[cw][n] = Cb(bf16,LDS) x X-frags(global->reg), 16x16x32 bf16 MFMA
//   softmax over cw in C/D layout (in-lane over mt/reg + shfl_xor 16,32 over quad)
//   A -> LDS (A-operand layout), X^T -> LDS (swizzled) -> matmul2 E[cw][d] accum in regs
//   epilogue: counts via shfl + LDS, E_part - count*C(fp32) atomicAdd into d_out.
// fp32 kept for: X2, C2, S, softmax, count*C  (bf16 only inside the two matmuls).

#define NN   16384
#define ND   128
#define NK   128
#define NC   64        // rows per chunk
#define TT   4         // chunks per block
#define CBP  136       // Cb LDS row stride (bf16 elems), 272B = 17*16 -> b128-aligned
#define XTP  72        // X^T LDS row stride, 144B
#define ATP  72        // A^T LDS row stride, 144B

typedef __bf16 bf16x8 __attribute__((ext_vector_type(8)));
typedef float  f32x4  __attribute__((ext_vector_type(4)));

__device__ __forceinline__ unsigned short f2bf(float x) {
    unsigned int u = __float_as_uint(x);
    u = (u + 0x7fffu + ((u >> 16) & 1u)) >> 16;   // round-to-nearest-even
    return (unsigned short)u;
}

__global__ __launch_bounds__(256, 2) void vq_fused(
    const float* __restrict__ Xg, const float* __restrict__ Cg,
    const float* __restrict__ Sg, float* __restrict__ Eg)
{
    __shared__ __align__(16) unsigned short sCb[NK * CBP];   // 34816 B
    __shared__ __align__(16) unsigned short sXT[ND * XTP];   // 18432 B
    __shared__ __align__(16) unsigned short sAt[NK * ATP];   // 18432 B
    __shared__ __align__(16) float2 sST[NK];                 // {S[k], S[k]*C2[k]}
    __shared__ __align__(16) float  sCntW[4][NK];            // [0] doubles as C2 temp

    const int tid  = threadIdx.x;
    const int lane = tid & 63;
    const int wave = tid >> 6;
    const int l15  = lane & 15;
    const int quad = lane >> 4;
    const int bid  = blockIdx.x;
    const int b    = bid >> 6;
    const int bg   = bid & 63;

    // ---- stage C -> bf16 LDS, compute C2 row sums (fp32) ----
    #pragma unroll
    for (int it = 0; it < 16; ++it) {
        int flat = it * 256 + tid;
        int row  = flat >> 5;          // 0..127
        int c4   = flat & 31;
        float4 v = reinterpret_cast<const float4*>(Cg)[row * 32 + c4];
        ushort4 h;
        h.x = f2bf(v.x); h.y = f2bf(v.y); h.z = f2bf(v.z); h.w = f2bf(v.w);
        *reinterpret_cast<ushort4*>(&sCb[row * CBP + c4 * 4]) = h;
        float ss = v.x*v.x + v.y*v.y + v.z*v.z + v.w*v.w;
        ss += __shfl_xor(ss, 1);
        ss += __shfl_xor(ss, 2);
        ss += __shfl_xor(ss, 4);
        ss += __shfl_xor(ss, 8);
        ss += __shfl_xor(ss, 16);
        if ((lane & 31) == 0) sCntW[0][row] = ss;
    }
    __syncthreads();
    if (tid < NK) {
        float s = Sg[tid];
        sST[tid] = make_float2(s, s * sCntW[0][tid]);
    }
    // (first in-loop __syncthreads orders sST before first use)

    f32x4 eacc[2][8];
    #pragma unroll
    for (int i = 0; i < 2; ++i)
        #pragma unroll
        for (int j = 0; j < 8; ++j)
            eacc[i][j] = (f32x4){0.f, 0.f, 0.f, 0.f};
    float cnt[8][4];
    #pragma unroll
    for (int mt = 0; mt < 8; ++mt)
        #pragma unroll
        for (int r = 0; r < 4; ++r) cnt[mt][r] = 0.f;

    const float* Xb = Xg + (size_t)b * (NN * ND);
    const int rloc = wave * 16 + l15;   // chunk-local row this lane stages

    #pragma unroll 1
    for (int t = 0; t < TT; ++t) {
        const int chunk = bg * TT + t;
        const float* rp = Xb + (size_t)(chunk * NC + rloc) * ND;

        // ---- load this wave's 16 rows as matmul1 B-fragments; fp32 X2 ----
        union CU { unsigned short u[8]; bf16x8 v; };
        CU cu[4];
        float x2 = 0.f;
        #pragma unroll
        for (int ks = 0; ks < 4; ++ks) {
            float4 va = *reinterpret_cast<const float4*>(rp + ks * 32 + quad * 8);
            float4 vb = *reinterpret_cast<const float4*>(rp + ks * 32 + quad * 8 + 4);
            x2 += va.x*va.x + va.y*va.y + va.z*va.z + va.w*va.w;
            x2 += vb.x*vb.x + vb.y*vb.y + vb.z*vb.z + vb.w*vb.w;
            cu[ks].u[0] = f2bf(va.x); cu[ks].u[1] = f2bf(va.y);
            cu[ks].u[2] = f2bf(va.z); cu[ks].u[3] = f2bf(va.w);
            cu[ks].u[4] = f2bf(vb.x); cu[ks].u[5] = f2bf(vb.y);
            cu[ks].u[6] = f2bf(vb.z); cu[ks].u[7] = f2bf(vb.w);
        }
        x2 += __shfl_xor(x2, 16);
        x2 += __shfl_xor(x2, 32);       // full X2 of row (chunk*64 + rloc)

        __syncthreads();                // (A) prev chunk's matmul2 reads done

        // ---- scatter X^T (swizzle r by bits of d>>3 to dodge bank conflicts) ----
        #pragma unroll
        for (int ks = 0; ks < 4; ++ks) {
            #pragma unroll
            for (int j = 0; j < 8; ++j) {
                int d  = ks * 32 + quad * 8 + j;
                int rs = rloc ^ (((d >> 3) & 3) << 3);
                sXT[d * XTP + rs] = cu[ks].u[j];
            }
        }

        // ---- matmul1: DT[cw][n] = C x X^T  (A = Cb tile, B = staged frags) ----
        f32x4 dacc[8];
        #pragma unroll
        for (int mt = 0; mt < 8; ++mt) {
            f32x4 acc = (f32x4){0.f, 0.f, 0.f, 0.f};
            #pragma unroll
            for (int ks = 0; ks < 4; ++ks) {
                bf16x8 af = *reinterpret_cast<const bf16x8*>(
                    &sCb[(mt * 16 + l15) * CBP + ks * 32 + quad * 8]);
                acc = __builtin_amdgcn_mfma_f32_16x16x32_bf16(af, cu[ks].v, acc, 0, 0, 0);
            }
            dacc[mt] = acc;
        }

        // ---- softmax over cw (lane's column n = rloc) ----
        float mx = -3.0e38f;
        #pragma unroll
        for (int mt = 0; mt < 8; ++mt) {
            #pragma unroll
            for (int r = 0; r < 4; ++r) {
                float2 st = sST[mt * 16 + quad * 4 + r];
                float dv = st.x * fmaf(-2.f, dacc[mt][r], x2) + st.y;  // S*(X2-2XC)+S*C2
                dacc[mt][r] = dv;
                mx = fmaxf(mx, dv);
            }
        }
        mx = fmaxf(mx, __shfl_xor(mx, 16));
        mx = fmaxf(mx, __shfl_xor(mx, 32));
        float ls = 0.f;
        #pragma unroll
        for (int mt = 0; mt < 8; ++mt) {
            #pragma unroll
            for (int r = 0; r < 4; ++r) {
                float e = __expf(dacc[mt][r] - mx);
                dacc[mt][r] = e;
                ls += e;
            }
        }
        ls += __shfl_xor(ls, 16);
        ls += __shfl_xor(ls, 32);
        const float inv = 1.0f / ls;

        // ---- A -> LDS (A-operand layout: rows=cw, cols=n), count accumulate ----
        #pragma unroll
        for (int mt = 0; mt < 8; ++mt) {
            #pragma unroll
            for (int r = 0; r < 4; ++r) {
                float a = dacc[mt][r] * inv;
                cnt[mt][r] += a;
                sAt[(mt * 16 + quad * 4 + r) * ATP + rloc] = f2bf(a);
            }
        }

        __syncthreads();                // (B) X^T and A^T visible to all waves

        // ---- matmul2: E[cw][d] += A x X ; wave owns cw in [32*wave, 32*wave+32) ----
        #pragma unroll
        for (int mt2 = 0; mt2 < 2; ++mt2) {
            const int cwrow = wave * 32 + mt2 * 16 + l15;
            bf16x8 a0 = *reinterpret_cast<const bf16x8*>(&sAt[cwrow * ATP + quad * 8]);
            bf16x8 a1 = *reinterpret_cast<const bf16x8*>(&sAt[cwrow * ATP + 32 + quad * 8]);
            #pragma unroll
            for (int dt = 0; dt < 8; ++dt) {
                const int drow = dt * 16 + l15;
                const int sw = ((drow >> 3) & 3) << 3;
                const unsigned short* xp = &sXT[drow * XTP];
                bf16x8 b0 = *reinterpret_cast<const bf16x8*>(&xp[(quad * 8) ^ sw]);
                bf16x8 b1 = *reinterpret_cast<const bf16x8*>(&xp[(32 + quad * 8) ^ sw]);
                eacc[mt2][dt] = __builtin_amdgcn_mfma_f32_16x16x32_bf16(a0, b0, eacc[mt2][dt], 0, 0, 0);
                eacc[mt2][dt] = __builtin_amdgcn_mfma_f32_16x16x32_bf16(a1, b1, eacc[mt2][dt], 0, 0, 0);
            }
        }
    }

    // ---- counts: reduce over wave's 16 n-columns, publish per-wave to LDS ----
    #pragma unroll
    for (int mt = 0; mt < 8; ++mt) {
        #pragma unroll
        for (int r = 0; r < 4; ++r) {
            float c = cnt[mt][r];
            c += __shfl_xor(c, 1);
            c += __shfl_xor(c, 2);
            c += __shfl_xor(c, 4);
            c += __shfl_xor(c, 8);
            if (l15 == 0) sCntW[wave][mt * 16 + quad * 4 + r] = c;
        }
    }
    __syncthreads();

    // ---- epilogue: E_part - count*C (fp32), atomic add into output ----
    float* Eb = Eg + b * (NK * ND);
    #pragma unroll
    for (int mt2 = 0; mt2 < 2; ++mt2) {
        #pragma unroll
        for (int r = 0; r < 4; ++r) {
            const int cw = wave * 32 + mt2 * 16 + quad * 4 + r;
            const float cc = sCntW[0][cw] + sCntW[1][cw] + sCntW[2][cw] + sCntW[3][cw];
            const float* crow = Cg + cw * ND;
            #pragma unroll
            for (int dt = 0; dt < 8; ++dt) {
                const int d = dt * 16 + l15;
                float val = eacc[mt2][dt][r] - cc * crow[d];
                unsafeAtomicAdd(&Eb[cw * ND + d], val);
            }
        }
    }
}

extern "C" void kernel_launch(void* const* d_in, const int* in_sizes, int n_in,
                              void* d_out, int out_size, void* d_ws, size_t ws_size,
                              hipStream_t stream) {
    const float* X = (const float*)d_in[0];
    const float* C = (const float*)d_in[1];
    const float* S = (const float*)d_in[2];
    float* E = (float*)d_out;
    (void)d_ws; (void)ws_size; (void)n_in; (void)in_sizes;
    hipMemsetAsync(d_out, 0, (size_t)out_size * sizeof(float), stream);
    hipLaunchKernelGGL(vq_fused, dim3(512), dim3(256), 0, stream, X, C, S, E);
}